// Round 9
// baseline (137.776 us; speedup 1.0000x reference)
//
#include <hip/hip_runtime.h>

#define TT 2048

__device__ __forceinline__ float b2f(unsigned short h) {
    union { unsigned int u; float f; } x; x.u = ((unsigned int)h) << 16; return x.f;
}
__device__ __forceinline__ unsigned short f2b(float f) {
    union { float f; unsigned int u; } x; x.f = f;
    unsigned int r = x.u + 0x7fffu + ((x.u >> 16) & 1u);  // RNE
    return (unsigned short)(r >> 16);
}
__device__ __forceinline__ float ldsc(const void* p, bool bf) {
    return bf ? b2f(*(const unsigned short*)p) : *(const float*)p;
}

// One wave per row. Lane chunk = 16 B (4 f32 / 8 bf16), so global I/O is
// naturally coalesced (1 KiB/instr) with NO LDS transpose. A row = NSEG
// wave-segments chained by a 2-float affine carry:
//   segment map: s_out = M s_in + b,  M = A^LPS (same for all lanes)
//   lane start  = W_lane * carry + E_lane,  W_lane = M^lane (precomputed once)
template<bool BF>
__device__ void run_row(
    const void* __restrict__ u_in, void* __restrict__ out,
    int rows, int b, int lane,
    float dt, float cc, float kk, float inv_m,
    float im, float is, float om, float inv_os)
{
    constexpr int LPS  = BF ? 8 : 4;   // elems per lane per segment (16 B)
    constexpr int NSEG = BF ? 4 : 8;   // segments per row (TT/(64*LPS))
    constexpr int ES   = BF ? 2 : 4;

    const float a21 = -dt * kk * inv_m;
    const float a22 = 1.0f - dt * cc * inv_m;
    const float dtm = dt * inv_m;

    // ---- level matrices L[k] = (A^LPS)^(2^k), k=0..5 (loop-invariant) ----
    float L[6][4];
    {
        float m00 = 1.f, m01 = dt, m10 = a21, m11 = a22;   // A
        constexpr int SQ = BF ? 3 : 2;                     // A^LPS
        #pragma unroll
        for (int i = 0; i < SQ; i++) {
            float t00=m00*m00+m01*m10, t01=m00*m01+m01*m11;
            float t10=m10*m00+m11*m10, t11=m10*m01+m11*m11;
            m00=t00; m01=t01; m10=t10; m11=t11;
        }
        #pragma unroll
        for (int k = 0; k < 6; k++) {
            L[k][0]=m00; L[k][1]=m01; L[k][2]=m10; L[k][3]=m11;
            float t00=m00*m00+m01*m10, t01=m00*m01+m01*m11;
            float t10=m10*m00+m11*m10, t11=m10*m01+m11*m11;
            m00=t00; m01=t01; m10=t10; m11=t11;
        }
    }
    // ---- W = (A^LPS)^lane via square-and-multiply on lane bits (once) ----
    // Seed = IDENTITY (r8 bug: w11 was 0 -> v-carry dropped).
    float w00 = 1.f, w01 = 0.f, w10 = 0.f, w11 = 1.f;
    #pragma unroll
    for (int k = 0; k < 6; k++) {
        if ((lane >> k) & 1) {
            float t00 = L[k][0]*w00 + L[k][1]*w10;
            float t01 = L[k][0]*w01 + L[k][1]*w11;
            float t10 = L[k][2]*w00 + L[k][3]*w10;
            float t11 = L[k][2]*w01 + L[k][3]*w11;
            w00=t00; w01=t01; w10=t10; w11=t11;
        }
    }

    const char* gin  = (const char*)u_in + (size_t)b * TT * ES;
    char*       gout = (char*)out        + (size_t)b * TT * ES;

    float cx = 0.f, cv = 0.f;   // carry state (wave-uniform value)

    uint4 cur = *(const uint4*)(gin + (size_t)lane * 16);

    #pragma unroll
    for (int seg = 0; seg < NSEG; seg++) {
        // prefetch next segment (4 regs; flies across this segment's compute)
        uint4 nxt = cur;
        if (seg + 1 < NSEG)
            nxt = *(const uint4*)(gin + (size_t)(seg + 1) * 1024 + (size_t)lane * 16);

        // ---- unpack ----
        float uf[LPS];
        if (BF) {
            unsigned int ws[4] = {cur.x, cur.y, cur.z, cur.w};
            #pragma unroll
            for (int q = 0; q < 4; q++) {
                uf[q*2 + 0] = b2f((unsigned short)(ws[q] & 0xffffu));
                uf[q*2 + 1] = b2f((unsigned short)(ws[q] >> 16));
            }
        } else {
            uf[0] = __uint_as_float(cur.x);
            uf[1] = __uint_as_float(cur.y);
            uf[2] = __uint_as_float(cur.z);
            uf[3] = __uint_as_float(cur.w);
        }

        // ---- pass 1: local recurrence from zero; u -> u_p in place ----
        float px = 0.f, pv = 0.f;
        #pragma unroll
        for (int i = 0; i < LPS; i++) {
            float up = uf[i] * is + im;
            uf[i] = up;
            float nx = px + dt * pv;
            float nv = a21 * px + a22 * pv + dtm * up;
            px = nx; pv = nv;
        }

        // ---- Kogge-Stone inclusive affine scan (precomputed level mats) ----
        #pragma unroll
        for (int k = 0; k < 6; k++) {
            float rx = __shfl_up(px, 1 << k, 64);
            float rv = __shfl_up(pv, 1 << k, 64);
            if (lane >= (1 << k)) {
                px = L[k][0]*rx + L[k][1]*rv + px;
                pv = L[k][2]*rx + L[k][3]*rv + pv;
            }
        }

        // ---- exclusive prefix + carry injection: start = W*c + E ----
        float ex = __shfl_up(px, 1, 64);
        float ev = __shfl_up(pv, 1, 64);
        if (lane == 0) { ex = 0.f; ev = 0.f; }
        float x = w00*cx + w01*cv + ex;
        float v = w10*cx + w11*cv + ev;

        // ---- pass 2: replay with true start state, y into uf ----
        #pragma unroll
        for (int i = 0; i < LPS; i++) {
            float up = uf[i];
            float nx = x + dt * v;
            float nv = a21 * x + a22 * v + dtm * up;
            float ay = (up - cc * nv - kk * nx) * inv_m;
            uf[i] = (ay - om) * inv_os;
            x = nx; v = nv;
        }

        // ---- carry out = lane 63's end state (broadcast) ----
        cx = __shfl(x, 63, 64);
        cv = __shfl(v, 63, 64);

        // ---- pack + coalesced store ----
        uint4 o;
        if (BF) {
            o.x = (unsigned)f2b(uf[0]) | ((unsigned)f2b(uf[1]) << 16);
            o.y = (unsigned)f2b(uf[2]) | ((unsigned)f2b(uf[3]) << 16);
            o.z = (unsigned)f2b(uf[4]) | ((unsigned)f2b(uf[5]) << 16);
            o.w = (unsigned)f2b(uf[6]) | ((unsigned)f2b(uf[7]) << 16);
        } else {
            o.x = __float_as_uint(uf[0]);
            o.y = __float_as_uint(uf[1]);
            o.z = __float_as_uint(uf[2]);
            o.w = __float_as_uint(uf[3]);
        }
        *(uint4*)(gout + (size_t)seg * 1024 + (size_t)lane * 16) = o;

        cur = nxt;
    }

    // ---- final state (every lane holds it via the carry broadcast) ----
    if (lane == 0) {
        if (BF) {
            unsigned short* ob = (unsigned short*)out;
            size_t so = (size_t)rows * TT + (size_t)b * 2;
            *(unsigned int*)(ob + so) =
                (unsigned)f2b(cx) | ((unsigned)f2b(cv) << 16);
        } else {
            float* of = (float*)out;
            size_t so = (size_t)rows * TT + (size_t)b * 2;
            *(float2*)(of + so) = make_float2(cx, cv);
        }
    }
}

__global__ __launch_bounds__(256, 4) void phys_scan(
    const void* __restrict__ u_in,
    const void* __restrict__ p_dt, const void* __restrict__ p_m,
    const void* __restrict__ p_c,  const void* __restrict__ p_k,
    const void* __restrict__ p_im, const void* __restrict__ p_is,
    const void* __restrict__ p_om, const void* __restrict__ p_os,
    void* __restrict__ out, int rows)
{
    const int lane = threadIdx.x & 63;
    const int b = blockIdx.x * 4 + (threadIdx.x >> 6);
    if (b >= rows) return;

    // dtype probe: m==1.0 -> f32 low ushort is 0x0000, bf16 is 0x3F80
    const bool bf = (((const unsigned short*)p_m)[0] != 0);

    const float dt = ldsc(p_dt, bf);
    const float mm = ldsc(p_m,  bf);
    const float cc = ldsc(p_c,  bf);
    const float kk = ldsc(p_k,  bf);
    const float im = ldsc(p_im, bf);
    const float is = ldsc(p_is, bf);
    const float om = ldsc(p_om, bf);
    const float os = ldsc(p_os, bf);
    const float inv_m  = 1.0f / mm;
    const float inv_os = 1.0f / os;

    if (bf) run_row<true >(u_in, out, rows, b, lane,
                           dt, cc, kk, inv_m, im, is, om, inv_os);
    else    run_row<false>(u_in, out, rows, b, lane,
                           dt, cc, kk, inv_m, im, is, om, inv_os);
}

extern "C" void kernel_launch(void* const* d_in, const int* in_sizes, int n_in,
                              void* d_out, int out_size, void* d_ws, size_t ws_size,
                              hipStream_t stream) {
    const int rows = in_sizes[0] / TT;          // 8192
    const int blocks = (rows + 3) / 4;          // 1 row per wave, 4 waves/block
    hipLaunchKernelGGL(phys_scan, dim3(blocks), dim3(256), 0, stream,
                       d_in[0], d_in[1], d_in[2], d_in[3], d_in[4],
                       d_in[5], d_in[6], d_in[7], d_in[8],
                       d_out, rows);
}

// Round 10
// 128.374 us; speedup vs baseline: 1.0732x; 1.0732x over previous
//
#include <hip/hip_runtime.h>

#define TT 2048

__device__ __forceinline__ float b2f(unsigned short h) {
    union { unsigned int u; float f; } x; x.u = ((unsigned int)h) << 16; return x.f;
}
__device__ __forceinline__ unsigned short f2b(float f) {
    union { float f; unsigned int u; } x; x.f = f;
    unsigned int r = x.u + 0x7fffu + ((x.u >> 16) & 1u);  // RNE
    return (unsigned short)(r >> 16);
}
__device__ __forceinline__ float ldsc(const void* p, bool bf) {
    return bf ? b2f(*(const unsigned short*)p) : *(const float*)p;
}
// 16B-unit XOR swizzle (involution): W[swz(q)] = G[q]. global_load_lds writes
// LDS linearly, so the per-lane GLOBAL source is pre-swizzled; reads use
// W[swz(p)] == G[p]. Verified r3/r4/r5 (passed, conflicts negligible).
__device__ __forceinline__ int swz(int u) { return u ^ ((u >> 3) & 7); }

// async global->LDS, 16B per lane; lds_base must be wave-uniform.
__device__ __forceinline__ void gload16(const void* g, void* lds_base) {
    __builtin_amdgcn_global_load_lds(
        (const __attribute__((address_space(1))) void*)g,
        (__attribute__((address_space(3))) void*)lds_base,
        16, 0, 0);
}

template<bool BF>
__device__ __forceinline__ void issue_row_loads(const void* u_in, int r, int lane, uint4* Wb) {
    constexpr int NLD = BF ? 4 : 8;
    constexpr int ES  = BF ? 2 : 4;
    const char* g = (const char*)u_in + (size_t)r * TT * ES;
    #pragma unroll
    for (int j = 0; j < NLD; j++)
        gload16(g + (size_t)swz(j * 64 + lane) * 16, (char*)Wb + j * 1024);
}

template<bool BF>
__device__ void run_wave(
    const void* __restrict__ u_in, void* __restrict__ out,
    int rows, int row0, int stride, int lane,
    uint4* __restrict__ U0, uint4* __restrict__ U1,
    float dt, float cc, float kk, float inv_m,
    float im, float is, float om, float inv_os)
{
    constexpr int NLD = BF ? 4 : 8;   // uint4 units per row per lane
    constexpr int ES  = BF ? 2 : 4;

    const float a21 = -dt * kk * inv_m;
    const float a22 = 1.0f - dt * cc * inv_m;
    const float dtm = dt * inv_m;

    // ---- A^16 (wave-uniform, once per wave): 4 squarings of A ----
    float q00 = 1.f, q01 = dt, q10 = a21, q11 = a22;
    #pragma unroll
    for (int i = 0; i < 4; i++) {
        float t00=q00*q00+q01*q10, t01=q00*q01+q01*q11;
        float t10=q10*q00+q11*q10, t11=q10*q01+q11*q11;
        q00=t00; q01=t01; q10=t10; q11=t11;
    }

    // ---- prologue: row0's loads into U0 (async, zero VGPR) ----
    issue_row_loads<BF>(u_in, row0, lane, U0);

    int p = 0;
    bool first = true;
    for (int r = row0; r < rows; r += stride) {
        uint4* W  = p ? U1 : U0;   // current row's u (later its y staging)
        uint4* Wn = p ? U0 : U1;   // next row's prefetch target

        // Steady state outstanding VMEM, oldest first:
        //   loads(r)[NLD] (issued at TOP of iter r-1), stores(r-1)[NLD+1]
        // -> wait "all but newest NLD+1" to guarantee loads(r) landed.
        if (first)      { asm volatile("s_waitcnt vmcnt(0)" ::: "memory"); }
        else if (BF)    { asm volatile("s_waitcnt vmcnt(5)" ::: "memory"); }
        else            { asm volatile("s_waitcnt vmcnt(9)" ::: "memory"); }
        __builtin_amdgcn_sched_barrier(0);

        // ---- PREFETCH FIRST: next row's loads fly across the whole compute
        const int rn = r + stride;
        if (rn < rows) issue_row_loads<BF>(u_in, rn, lane, Wn);
        __builtin_amdgcn_sched_barrier(0);

        // ---- read lane's contiguous 32 elems from LDS ----
        float uf[32];
        if (BF) {
            #pragma unroll
            for (int m = 0; m < 4; m++) {
                uint4 w = W[swz(lane * 4 + m)];
                unsigned int ws[4] = {w.x, w.y, w.z, w.w};
                #pragma unroll
                for (int q = 0; q < 4; q++) {
                    uf[m*8 + q*2 + 0] = b2f((unsigned short)(ws[q] & 0xffffu));
                    uf[m*8 + q*2 + 1] = b2f((unsigned short)(ws[q] >> 16));
                }
            }
        } else {
            #pragma unroll
            for (int m = 0; m < 8; m++) {
                uint4 w = W[swz(lane * 8 + m)];
                uf[m*4+0] = __uint_as_float(w.x);
                uf[m*4+1] = __uint_as_float(w.y);
                uf[m*4+2] = __uint_as_float(w.z);
                uf[m*4+3] = __uint_as_float(w.w);
            }
        }

        // ---- pass 1, chain-split (2x ILP): two independent 16-step chains
        //      from zero state; u -> u_p in place.  s32 = A^16*sA + sB.
        float ax = 0.f, av = 0.f, bx2 = 0.f, bv2 = 0.f;
        #pragma unroll
        for (int i = 0; i < 16; i++) {
            float upA = uf[i] * is + im;
            uf[i] = upA;
            float nxA = ax + dt * av;
            float nvA = a21 * ax + a22 * av + dtm * upA;
            ax = nxA; av = nvA;

            float upB = uf[16 + i] * is + im;
            uf[16 + i] = upB;
            float nxB = bx2 + dt * bv2;
            float nvB = a21 * bx2 + a22 * bv2 + dtm * upB;
            bx2 = nxB; bv2 = nvB;
        }
        float px = q00*ax + q01*av + bx2;
        float pv = q10*ax + q11*av + bv2;

        // ---- Kogge-Stone inclusive affine scan across the wave ----
        // level matrix starts at A^32 = (A^16)^2
        float m00 = q00*q00 + q01*q10;
        float m01 = q00*q01 + q01*q11;
        float m10 = q10*q00 + q11*q10;
        float m11 = q10*q01 + q11*q11;
        #pragma unroll
        for (int o = 1; o < 64; o <<= 1) {
            float rx = __shfl_up(px, o, 64);
            float rv = __shfl_up(pv, o, 64);
            if (lane >= o) {
                px = m00*rx + m01*rv + px;
                pv = m10*rx + m11*rv + pv;
            }
            if (o < 32) {   // square level matrix (off the shfl dep chain)
                float t00 = m00*m00 + m01*m10;
                float t01 = m00*m01 + m01*m11;
                float t10 = m10*m00 + m11*m10;
                float t11 = m10*m01 + m11*m11;
                m00=t00; m01=t01; m10=t10; m11=t11;
            }
        }

        float ex = __shfl_up(px, 1, 64);
        float ev = __shfl_up(pv, 1, 64);
        if (lane == 0) { ex = 0.f; ev = 0.f; }

        // ---- pass 2, chain-split (2x ILP): chain A replays i=0..15 from s0;
        //      chain B replays i=16..31 from s16 = A^16*s0 + sA (sA live).
        float xA = ex, vA = ev;
        float xB = q00*ex + q01*ev + ax;
        float vB = q10*ex + q11*ev + av;
        #pragma unroll
        for (int i = 0; i < 16; i++) {
            float upA = uf[i];
            float nxA = xA + dt * vA;
            float nvA = a21 * xA + a22 * vA + dtm * upA;
            float ayA = (upA - cc * nvA - kk * nxA) * inv_m;
            uf[i] = (ayA - om) * inv_os;
            xA = nxA; vA = nvA;

            float upB = uf[16 + i];
            float nxB = xB + dt * vB;
            float nvB = a21 * xB + a22 * vB + dtm * upB;
            float ayB = (upB - cc * nvB - kk * nxB) * inv_m;
            uf[16 + i] = (ayB - om) * inv_os;
            xB = nxB; vB = nvB;
        }

        // ---- stage y into W (u consumed; same-wave DS is in-order) ----
        if (BF) {
            #pragma unroll
            for (int m = 0; m < 4; m++) {
                uint4 w;
                w.x = (unsigned)f2b(uf[m*8+0]) | ((unsigned)f2b(uf[m*8+1]) << 16);
                w.y = (unsigned)f2b(uf[m*8+2]) | ((unsigned)f2b(uf[m*8+3]) << 16);
                w.z = (unsigned)f2b(uf[m*8+4]) | ((unsigned)f2b(uf[m*8+5]) << 16);
                w.w = (unsigned)f2b(uf[m*8+6]) | ((unsigned)f2b(uf[m*8+7]) << 16);
                W[swz(lane * 4 + m)] = w;
            }
        } else {
            #pragma unroll
            for (int m = 0; m < 8; m++) {
                uint4 w;
                w.x = __float_as_uint(uf[m*4+0]);
                w.y = __float_as_uint(uf[m*4+1]);
                w.z = __float_as_uint(uf[m*4+2]);
                w.w = __float_as_uint(uf[m*4+3]);
                W[swz(lane * 8 + m)] = w;
            }
        }
        __builtin_amdgcn_wave_barrier();

        // ---- coalesced store of y from LDS + packed state store ----
        {
            uint4* g = (uint4*)((char*)out + (size_t)r * TT * ES);
            #pragma unroll
            for (int j = 0; j < NLD; j++) {
                uint4 t = W[swz(j * 64 + lane)];
                g[j * 64 + lane] = t;
            }
        }
        if (lane == 63) {   // final state = lane 63's inclusive scan value
            if (BF) {
                unsigned short* ob = (unsigned short*)out;
                size_t so = (size_t)rows * TT + (size_t)r * 2;
                *(unsigned int*)(ob + so) =
                    (unsigned)f2b(px) | ((unsigned)f2b(pv) << 16);
            } else {
                float* of = (float*)out;
                size_t so = (size_t)rows * TT + (size_t)r * 2;
                *(float2*)(of + so) = make_float2(px, pv);
            }
        }

        p ^= 1;
        first = false;
    }
}

__global__ __launch_bounds__(128, 2) void phys_scan(
    const void* __restrict__ u_in,
    const void* __restrict__ p_dt, const void* __restrict__ p_m,
    const void* __restrict__ p_c,  const void* __restrict__ p_k,
    const void* __restrict__ p_im, const void* __restrict__ p_is,
    const void* __restrict__ p_om, const void* __restrict__ p_os,
    void* __restrict__ out, int rows, int stride)
{
    __shared__ uint4 smem[2][2][512];   // 2 waves x double-buffer x 8 KiB = 32 KiB
    const int lane = threadIdx.x & 63;
    const int wid  = threadIdx.x >> 6;
    const int row0 = blockIdx.x * 2 + wid;
    if (row0 >= rows) return;

    // dtype probe: m==1.0 -> f32 low ushort is 0x0000, bf16 is 0x3F80
    const bool bf = (((const unsigned short*)p_m)[0] != 0);

    const float dt = ldsc(p_dt, bf);
    const float mm = ldsc(p_m,  bf);
    const float cc = ldsc(p_c,  bf);
    const float kk = ldsc(p_k,  bf);
    const float im = ldsc(p_im, bf);
    const float is = ldsc(p_is, bf);
    const float om = ldsc(p_om, bf);
    const float os = ldsc(p_os, bf);
    const float inv_m  = 1.0f / mm;
    const float inv_os = 1.0f / os;

    if (bf) run_wave<true >(u_in, out, rows, row0, stride, lane,
                            smem[wid][0], smem[wid][1],
                            dt, cc, kk, inv_m, im, is, om, inv_os);
    else    run_wave<false>(u_in, out, rows, row0, stride, lane,
                            smem[wid][0], smem[wid][1],
                            dt, cc, kk, inv_m, im, is, om, inv_os);
}

extern "C" void kernel_launch(void* const* d_in, const int* in_sizes, int n_in,
                              void* d_out, int out_size, void* d_ws, size_t ws_size,
                              hipStream_t stream) {
    const int rows = in_sizes[0] / TT;          // 8192
    // Persistent waves: 1024 blocks x 128 thr (2 waves, 32 KiB LDS) ->
    // 5 blocks/CU = 10 waves/CU; 2048 waves each pipelining 4 rows.
    int blocks = (rows + 1) / 2;
    if (blocks > 1024) blocks = 1024;
    const int stride = blocks * 2;
    hipLaunchKernelGGL(phys_scan, dim3(blocks), dim3(128), 0, stream,
                       d_in[0], d_in[1], d_in[2], d_in[3], d_in[4],
                       d_in[5], d_in[6], d_in[7], d_in[8],
                       d_out, rows, stride);
}

// Round 12
// 125.953 us; speedup vs baseline: 1.0939x; 1.0192x over previous
//
#include <hip/hip_runtime.h>

#define TT 2048

typedef unsigned int u32x4 __attribute__((ext_vector_type(4)));  // native vec for NT store

__device__ __forceinline__ float b2f(unsigned short h) {
    union { unsigned int u; float f; } x; x.u = ((unsigned int)h) << 16; return x.f;
}
__device__ __forceinline__ unsigned short f2b(float f) {
    union { float f; unsigned int u; } x; x.f = f;
    unsigned int r = x.u + 0x7fffu + ((x.u >> 16) & 1u);  // RNE
    return (unsigned short)(r >> 16);
}
__device__ __forceinline__ float ldsc(const void* p, bool bf) {
    return bf ? b2f(*(const unsigned short*)p) : *(const float*)p;
}
// 16B-unit XOR swizzle (involution): W[swz(q)] = G[q]. global_load_lds writes
// LDS linearly, so the per-lane GLOBAL source is pre-swizzled; reads use
// W[swz(p)] == G[p]. Verified r3/r4/r5 (passed, conflicts negligible).
__device__ __forceinline__ int swz(int u) { return u ^ ((u >> 3) & 7); }

// async global->LDS, 16B per lane; lds_base must be wave-uniform.
__device__ __forceinline__ void gload16(const void* g, void* lds_base) {
    __builtin_amdgcn_global_load_lds(
        (const __attribute__((address_space(1))) void*)g,
        (__attribute__((address_space(3))) void*)lds_base,
        16, 0, 0);
}

template<bool BF>
__device__ __forceinline__ void issue_row_loads(const void* u_in, int r, int lane, uint4* Wb) {
    constexpr int NLD = BF ? 4 : 8;
    constexpr int ES  = BF ? 2 : 4;
    const char* g = (const char*)u_in + (size_t)r * TT * ES;
    #pragma unroll
    for (int j = 0; j < NLD; j++)
        gload16(g + (size_t)swz(j * 64 + lane) * 16, (char*)Wb + j * 1024);
}

template<bool BF>
__device__ void run_wave(
    const void* __restrict__ u_in, void* __restrict__ out,
    int rows, int row0, int stride, int lane,
    uint4* __restrict__ U0, uint4* __restrict__ U1,
    float dt, float cc, float kk, float inv_m,
    float im, float is, float om, float inv_os)
{
    constexpr int NLD = BF ? 4 : 8;   // uint4 units per row per lane
    constexpr int ES  = BF ? 2 : 4;

    const float a21 = -dt * kk * inv_m;
    const float a22 = 1.0f - dt * cc * inv_m;
    const float dtm = dt * inv_m;

    // ---- prologue: row0's loads into U0 (async, zero VGPR) ----
    issue_row_loads<BF>(u_in, row0, lane, U0);

    int p = 0;
    bool first = true;
    for (int r = row0; r < rows; r += stride) {
        uint4* W  = p ? U1 : U0;   // current row's u (later its y staging)
        uint4* Wn = p ? U0 : U1;   // next row's prefetch target

        // Steady state outstanding VMEM, oldest first:
        //   loads(r)[NLD] (issued at TOP of iter r-1), stores(r-1)[NLD+1]
        // -> wait "all but newest NLD+1" to guarantee loads(r) landed.
        if (first)      { asm volatile("s_waitcnt vmcnt(0)" ::: "memory"); }
        else if (BF)    { asm volatile("s_waitcnt vmcnt(5)" ::: "memory"); }
        else            { asm volatile("s_waitcnt vmcnt(9)" ::: "memory"); }
        __builtin_amdgcn_sched_barrier(0);

        // ---- PREFETCH FIRST: next row's loads fly across the whole compute
        const int rn = r + stride;
        if (rn < rows) issue_row_loads<BF>(u_in, rn, lane, Wn);
        __builtin_amdgcn_sched_barrier(0);

        // ---- read lane's contiguous 32 elems from LDS ----
        float uf[32];
        if (BF) {
            #pragma unroll
            for (int m = 0; m < 4; m++) {
                uint4 w = W[swz(lane * 4 + m)];
                unsigned int ws[4] = {w.x, w.y, w.z, w.w};
                #pragma unroll
                for (int q = 0; q < 4; q++) {
                    uf[m*8 + q*2 + 0] = b2f((unsigned short)(ws[q] & 0xffffu));
                    uf[m*8 + q*2 + 1] = b2f((unsigned short)(ws[q] >> 16));
                }
            }
        } else {
            #pragma unroll
            for (int m = 0; m < 8; m++) {
                uint4 w = W[swz(lane * 8 + m)];
                uf[m*4+0] = __uint_as_float(w.x);
                uf[m*4+1] = __uint_as_float(w.y);
                uf[m*4+2] = __uint_as_float(w.z);
                uf[m*4+3] = __uint_as_float(w.w);
            }
        }

        // ---- pass 1: local recurrence from zero state; u -> u_p in place ----
        float px = 0.f, pv = 0.f;
        #pragma unroll
        for (int i = 0; i < 32; i++) {
            float up = uf[i] * is + im;
            uf[i] = up;
            float nx = px + dt * pv;
            float nv = a21 * px + a22 * pv + dtm * up;
            px = nx; pv = nv;
        }

        // ---- M = A^32 via 5 squarings ----
        float m00 = 1.f, m01 = dt, m10 = a21, m11 = a22;
        #pragma unroll
        for (int i = 0; i < 5; i++) {
            float t00 = m00*m00 + m01*m10;
            float t01 = m00*m01 + m01*m11;
            float t10 = m10*m00 + m11*m10;
            float t11 = m10*m01 + m11*m11;
            m00=t00; m01=t01; m10=t10; m11=t11;
        }

        // ---- Kogge-Stone inclusive affine scan across the wave ----
        #pragma unroll
        for (int o = 1; o < 64; o <<= 1) {
            float rx = __shfl_up(px, o, 64);
            float rv = __shfl_up(pv, o, 64);
            if (lane >= o) {
                px = m00*rx + m01*rv + px;
                pv = m10*rx + m11*rv + pv;
            }
            if (o < 32) {
                float t00 = m00*m00 + m01*m10;
                float t01 = m00*m01 + m01*m11;
                float t10 = m10*m00 + m11*m10;
                float t11 = m10*m01 + m11*m11;
                m00=t00; m01=t01; m10=t10; m11=t11;
            }
        }

        float ex = __shfl_up(px, 1, 64);
        float ev = __shfl_up(pv, 1, 64);
        if (lane == 0) { ex = 0.f; ev = 0.f; }

        // ---- pass 2: replay with true start state, y into uf ----
        float x = ex, v = ev;
        #pragma unroll
        for (int i = 0; i < 32; i++) {
            float up = uf[i];
            float nx = x + dt * v;
            float nv = a21 * x + a22 * v + dtm * up;
            float ay = (up - cc * nv - kk * nx) * inv_m;
            uf[i] = (ay - om) * inv_os;
            x = nx; v = nv;
        }

        // ---- stage y into W (u consumed; same-wave DS is in-order) ----
        if (BF) {
            #pragma unroll
            for (int m = 0; m < 4; m++) {
                uint4 w;
                w.x = (unsigned)f2b(uf[m*8+0]) | ((unsigned)f2b(uf[m*8+1]) << 16);
                w.y = (unsigned)f2b(uf[m*8+2]) | ((unsigned)f2b(uf[m*8+3]) << 16);
                w.z = (unsigned)f2b(uf[m*8+4]) | ((unsigned)f2b(uf[m*8+5]) << 16);
                w.w = (unsigned)f2b(uf[m*8+6]) | ((unsigned)f2b(uf[m*8+7]) << 16);
                W[swz(lane * 4 + m)] = w;
            }
        } else {
            #pragma unroll
            for (int m = 0; m < 8; m++) {
                uint4 w;
                w.x = __float_as_uint(uf[m*4+0]);
                w.y = __float_as_uint(uf[m*4+1]);
                w.z = __float_as_uint(uf[m*4+2]);
                w.w = __float_as_uint(uf[m*4+3]);
                W[swz(lane * 8 + m)] = w;
            }
        }
        __builtin_amdgcn_wave_barrier();

        // ---- coalesced NON-TEMPORAL store of y from LDS (write-once stream:
        //      bypass L2 so the input stream keeps its L2/L3 residency) ----
        {
            u32x4* g = (u32x4*)((char*)out + (size_t)r * TT * ES);
            #pragma unroll
            for (int j = 0; j < NLD; j++) {
                uint4 t = W[swz(j * 64 + lane)];
                u32x4 tv = { t.x, t.y, t.z, t.w };
                __builtin_nontemporal_store(tv, &g[j * 64 + lane]);
            }
        }
        if (lane == 63) {   // final state = lane 63's inclusive scan value
            if (BF) {
                unsigned short* ob = (unsigned short*)out;
                size_t so = (size_t)rows * TT + (size_t)r * 2;
                *(unsigned int*)(ob + so) =
                    (unsigned)f2b(px) | ((unsigned)f2b(pv) << 16);
            } else {
                float* of = (float*)out;
                size_t so = (size_t)rows * TT + (size_t)r * 2;
                *(float2*)(of + so) = make_float2(px, pv);
            }
        }

        p ^= 1;
        first = false;
    }
}

__global__ __launch_bounds__(128, 2) void phys_scan(
    const void* __restrict__ u_in,
    const void* __restrict__ p_dt, const void* __restrict__ p_m,
    const void* __restrict__ p_c,  const void* __restrict__ p_k,
    const void* __restrict__ p_im, const void* __restrict__ p_is,
    const void* __restrict__ p_om, const void* __restrict__ p_os,
    void* __restrict__ out, int rows, int stride)
{
    __shared__ uint4 smem[2][2][512];   // 2 waves x double-buffer x 8 KiB = 32 KiB
    const int lane = threadIdx.x & 63;
    const int wid  = threadIdx.x >> 6;
    const int row0 = blockIdx.x * 2 + wid;
    if (row0 >= rows) return;

    // dtype probe: m==1.0 -> f32 low ushort is 0x0000, bf16 is 0x3F80
    const bool bf = (((const unsigned short*)p_m)[0] != 0);

    const float dt = ldsc(p_dt, bf);
    const float mm = ldsc(p_m,  bf);
    const float cc = ldsc(p_c,  bf);
    const float kk = ldsc(p_k,  bf);
    const float im = ldsc(p_im, bf);
    const float is = ldsc(p_is, bf);
    const float om = ldsc(p_om, bf);
    const float os = ldsc(p_os, bf);
    const float inv_m  = 1.0f / mm;
    const float inv_os = 1.0f / os;

    if (bf) run_wave<true >(u_in, out, rows, row0, stride, lane,
                            smem[wid][0], smem[wid][1],
                            dt, cc, kk, inv_m, im, is, om, inv_os);
    else    run_wave<false>(u_in, out, rows, row0, stride, lane,
                            smem[wid][0], smem[wid][1],
                            dt, cc, kk, inv_m, im, is, om, inv_os);
}

extern "C" void kernel_launch(void* const* d_in, const int* in_sizes, int n_in,
                              void* d_out, int out_size, void* d_ws, size_t ws_size,
                              hipStream_t stream) {
    const int rows = in_sizes[0] / TT;          // 8192
    // Persistent waves: 1024 blocks x 128 thr (2 waves, 32 KiB LDS) ->
    // 5 blocks/CU = 10 waves/CU; 2048 waves each pipelining 4 rows.
    int blocks = (rows + 1) / 2;
    if (blocks > 1024) blocks = 1024;
    const int stride = blocks * 2;
    hipLaunchKernelGGL(phys_scan, dim3(blocks), dim3(128), 0, stream,
                       d_in[0], d_in[1], d_in[2], d_in[3], d_in[4],
                       d_in[5], d_in[6], d_in[7], d_in[8],
                       d_out, rows, stride);
}